// Round 3
// baseline (195.366 us; speedup 1.0000x reference)
//
#include <hip/hip_runtime.h>

// SSIM (win=11, sigma=1.5, range=255), N=16 C=3 512x512 fp32 -> [16,502,502].
// R3: both separable convs on the MFMA pipe (mfma_f32_16x16x32_f16).
//
//   D[m][n] = sum_k A[m][k] * B[k][n],  B[k][n] = W[k-n] (banded weights,
//   constant per lane, shared by BOTH passes).
//
// Horizontal pass: A[m=row][k=col] from row-major staged f16 (ds_read_b128).
//   C-layout (row=(lane>>4)*4+reg, col=lane&15) => lane holds 4 consecutive
//   image rows at one outcol -> ds_write_b64 into transposed H_T[col][row].
// Vertical pass: A[m=outcol][k=row] from H_T (contiguous k -> ds_read_b128).
//   Wave w owns outcol chunk w for both passes -> no H->V barrier.
//
// Tile 64x16 outputs/block; staged region 26(+6 zero pad)x80, K padded to 32
// with zero weights (W[k-n]=0 for k-n>10). f16 data (x^2<=65025<65504).
// LDS: s_in 5x32x88 f16 (pitch 176B: 16B-aligned, bank-stride 12 balanced)
//      s_ht 5x64x40 f16 (pitch 80B:  16B-aligned, bank-stride 20 balanced)
//      total 53.8 kB -> 3 blocks/CU.

namespace {

constexpr int NN = 16, CC = 3, HH = 512, WW = 512;
constexpr int OH = HH - 10, OW = WW - 10;          // 502 x 502
constexpr int TW = 64, TH = 16;                    // output tile
constexpr int SROWS = 32, SCOLS = 80, SPITCH = 88; // staged f16 region
constexpr int HCOLS = 64, HROWS = 32, HPITCH = 40; // H^T f16
constexpr float C1c = 6.5025f;                     // (0.01*255)^2
constexpr float C2c = 58.5225f;                    // (0.03*255)^2

typedef _Float16 half8  __attribute__((ext_vector_type(8)));
typedef _Float16 half4  __attribute__((ext_vector_type(4)));
typedef float    floatv4 __attribute__((ext_vector_type(4)));

__device__ const float WF[11] = {
    0.00102838f, 0.00759876f, 0.03600077f, 0.10936069f, 0.21300553f,
    0.26601172f,
    0.21300553f, 0.10936069f, 0.03600077f, 0.00759876f, 0.00102838f
};

__global__ __launch_bounds__(256, 3)
void ssim_kernel(const float* __restrict__ X, const float* __restrict__ Y,
                 float* __restrict__ out)
{
    __shared__ __align__(16) _Float16 s_in[5][SROWS][SPITCH];
    __shared__ __align__(16) _Float16 s_ht[5][HCOLS][HPITCH];
    __shared__ _Float16 s_wtab[16];

    const int tid  = threadIdx.x;
    const int lane = tid & 63;
    const int wv   = tid >> 6;          // wave id = outcol chunk (4 x 16 cols)
    const int col0 = blockIdx.x * TW;
    const int row0 = blockIdx.y * TH;
    const int n    = blockIdx.z;

    if (tid < 16) s_wtab[tid] = (tid < 11) ? (_Float16)WF[tid] : (_Float16)0.f;
    __syncthreads();

    // banded weight fragment B[k][n] = W[k-n]; lane: n=lane&15, k=(lane>>4)*8+j
    half8 bfrag;
    {
        const int bn = lane & 15, kq = (lane >> 4) * 8;
        #pragma unroll
        for (int j = 0; j < 8; ++j) {
            int kk = kq + j - bn;
            kk = (kk < 0 || kk > 10) ? 11 : kk;   // index 11 holds 0
            bfrag[j] = s_wtab[kk];
        }
    }

    float acc[4] = {0.f, 0.f, 0.f, 0.f};

    const size_t plane = (size_t)HH * WW;
    const float* Xn = X + (size_t)n * CC * plane;
    const float* Yn = Y + (size_t)n * CC * plane;
    const bool fastcol = (col0 + SCOLS <= WW);    // blocks x=0..6

    const floatv4 zf = {0.f, 0.f, 0.f, 0.f};

    for (int ch = 0; ch < CC; ++ch) {
        const float* Xc = Xn + (size_t)ch * plane;
        const float* Yc = Yn + (size_t)ch * plane;

        // ---- staging: rows 0..25 real (clamped), rows 26..31 zero (only
        // ever multiplied by zero weights; must be finite) ----
        for (int i = tid; i < SROWS * (SCOLS / 4); i += 256) {   // 640 items
            int r = i / (SCOLS / 4), c4 = (i - r * (SCOLS / 4)) * 4;
            half4 hx, hy, hxx, hyy, hxy;
            if (r < 26) {
                int gr = row0 + r; gr = gr < HH ? gr : HH - 1;
                float4 vx, vy;
                if (fastcol) {
                    vx = *(const float4*)(Xc + (size_t)gr * WW + col0 + c4);
                    vy = *(const float4*)(Yc + (size_t)gr * WW + col0 + c4);
                } else {
                    float ax[4], ay[4];
                    #pragma unroll
                    for (int e = 0; e < 4; ++e) {
                        int gw = col0 + c4 + e; gw = gw < WW ? gw : WW - 1;
                        ax[e] = Xc[(size_t)gr * WW + gw];
                        ay[e] = Yc[(size_t)gr * WW + gw];
                    }
                    vx = make_float4(ax[0], ax[1], ax[2], ax[3]);
                    vy = make_float4(ay[0], ay[1], ay[2], ay[3]);
                }
                hx  = {(_Float16)vx.x, (_Float16)vx.y,
                       (_Float16)vx.z, (_Float16)vx.w};
                hy  = {(_Float16)vy.x, (_Float16)vy.y,
                       (_Float16)vy.z, (_Float16)vy.w};
                hxx = {(_Float16)(vx.x*vx.x), (_Float16)(vx.y*vx.y),
                       (_Float16)(vx.z*vx.z), (_Float16)(vx.w*vx.w)};
                hyy = {(_Float16)(vy.x*vy.x), (_Float16)(vy.y*vy.y),
                       (_Float16)(vy.z*vy.z), (_Float16)(vy.w*vy.w)};
                hxy = {(_Float16)(vx.x*vy.x), (_Float16)(vx.y*vy.y),
                       (_Float16)(vx.z*vy.z), (_Float16)(vx.w*vy.w)};
            } else {
                _Float16 z0 = (_Float16)0.f;
                hx = {z0,z0,z0,z0}; hy = hx; hxx = hx; hyy = hx; hxy = hx;
            }
            *(half4*)&s_in[0][r][c4] = hx;
            *(half4*)&s_in[1][r][c4] = hy;
            *(half4*)&s_in[2][r][c4] = hxx;
            *(half4*)&s_in[3][r][c4] = hyy;
            *(half4*)&s_in[4][r][c4] = hxy;
        }
        __syncthreads();

        // ---- H + V MFMA passes (wave-private col chunk; no barrier) ----
        floatv4 vfrag[5];
        #pragma unroll
        for (int q = 0; q < 5; ++q) {
            #pragma unroll
            for (int rc = 0; rc < 2; ++rc) {
                const half8 a = *(const half8*)
                    &s_in[q][rc*16 + (lane & 15)][wv*16 + (lane >> 4)*8];
                floatv4 d = __builtin_amdgcn_mfma_f32_16x16x32_f16(
                    a, bfrag, zf, 0, 0, 0);
                half4 h = {(_Float16)d[0], (_Float16)d[1],
                           (_Float16)d[2], (_Float16)d[3]};
                *(half4*)&s_ht[q][wv*16 + (lane & 15)][rc*16 + (lane >> 4)*4] = h;
            }
            const half8 av = *(const half8*)
                &s_ht[q][wv*16 + (lane & 15)][(lane >> 4)*8];
            vfrag[q] = __builtin_amdgcn_mfma_f32_16x16x32_f16(
                av, bfrag, zf, 0, 0, 0);
        }

        // ---- SSIM math on V fragments (fp32, in registers) ----
        // lane holds: outrow = lane&15, outcols = wv*16 + (lane>>4)*4 + p
        #pragma unroll
        for (int p = 0; p < 4; ++p) {
            float m1 = vfrag[0][p], m2 = vfrag[1][p];
            float exx = vfrag[2][p], eyy = vfrag[3][p], exy = vfrag[4][p];
            float m1s = m1*m1, m2s = m2*m2, m12 = m1*m2;
            float s1  = exx - m1s, s2 = eyy - m2s, s12 = exy - m12;
            float n1 = 2.f*m12 + C1c, d1 = m1s + m2s + C1c;
            float n2 = 2.f*s12 + C2c, d2 = s1 + s2 + C2c;
            acc[p] = fmaf(n1 * n2, __builtin_amdgcn_rcpf(d1 * d2), acc[p]);
        }
        __syncthreads();   // s_in reused next channel (s_ht is wave-private)
    }

    // ---- epilogue: 1 - mean over channels ----
    const int orow = row0 + (lane & 15);
    const int ocol = col0 + wv*16 + (lane >> 4)*4;
    if (orow < OH) {
        float r0v = 1.f - acc[0] * (1.f/3.f);
        float r1v = 1.f - acc[1] * (1.f/3.f);
        float r2v = 1.f - acc[2] * (1.f/3.f);
        float r3v = 1.f - acc[3] * (1.f/3.f);
        size_t base = ((size_t)n * OH + orow) * OW + ocol;
        if (ocol + 3 < OW) {
            *(float2*)(out + base)     = make_float2(r0v, r1v);
            *(float2*)(out + base + 2) = make_float2(r2v, r3v);
        } else {
            float rs[4] = {r0v, r1v, r2v, r3v};
            #pragma unroll
            for (int p = 0; p < 4; ++p)
                if (ocol + p < OW) out[base + p] = rs[p];
        }
    }
}

} // namespace

extern "C" void kernel_launch(void* const* d_in, const int* in_sizes, int n_in,
                              void* d_out, int out_size, void* d_ws, size_t ws_size,
                              hipStream_t stream) {
    const float* X = (const float*)d_in[0];
    const float* Y = (const float*)d_in[1];
    float* out = (float*)d_out;

    dim3 grid((OW + TW - 1) / TW,   // 8
              (OH + TH - 1) / TH,   // 32
              NN);                  // 16
    ssim_kernel<<<grid, 256, 0, stream>>>(X, Y, out);
}

// Round 4
// 146.536 us; speedup vs baseline: 1.3332x; 1.3332x over previous
//
#include <hip/hip_runtime.h>

// SSIM (win=11, sigma=1.5, range=255), N=16 C=3 512x512 fp32 -> [16,502,502].
// R4: occupancy attack (R3 was latency-bound: all pipes <20%, occ 20.75%).
//  - stage only x,y in LDS; x^2/y^2/xy A-fragments derived in registers
//    (elementwise v_pk_mul_f16 of the x/y fragments -- same lane layout)
//  - single ping-pong s_ht buffer (wave-private, per-wave DS ordering --
//    same-wave write->read round-trip validated by R3's pass)
//  - 64x32 tile (2 bands of 16 rows): H rows shared between bands
//    (3 H-MFMAs vs 4 per quantity), halo amortized, 2048 blocks
//  LDS 29.2 kB -> 5 blocks/CU; __launch_bounds__(256,4) caps VGPR at 128.
//
// MFMA scheme (mfma_f32_16x16x32_f16), B[k][n] = W[k-n] banded, both passes:
//  H: A[m=row][k=stagedcol] -> D[m=row][n=outcol]; C-layout lane holds
//     4 consecutive rows at one outcol -> ds_write_b64 transposed H_T.
//  V: A[m=outcol][k=row] from H_T (k contiguous -> ds_read_b128),
//     D[m=outcol][n=outrow]. Wave owns outcol chunk for both -> no barrier.

namespace {

constexpr int NN = 16, CC = 3, HH = 512, WW = 512;
constexpr int OH = HH - 10, OW = WW - 10;          // 502 x 502
constexpr int TW = 64, TH = 32;                    // output tile
constexpr int SROWS = 48, SREAL = 42;              // staged rows (42 real)
constexpr int SCOLS = 80, SPITCH = 88;             // staged cols, f16 pitch
constexpr int HPITCH = 48;                         // H_T row pitch (f16)
constexpr float C1c = 6.5025f;                     // (0.01*255)^2
constexpr float C2c = 58.5225f;                    // (0.03*255)^2

typedef _Float16 half8   __attribute__((ext_vector_type(8)));
typedef _Float16 half4   __attribute__((ext_vector_type(4)));
typedef float    floatv4 __attribute__((ext_vector_type(4)));

__device__ const float WF[11] = {
    0.00102838f, 0.00759876f, 0.03600077f, 0.10936069f, 0.21300553f,
    0.26601172f,
    0.21300553f, 0.10936069f, 0.03600077f, 0.00759876f, 0.00102838f
};

__global__ __launch_bounds__(256, 4)
void ssim_kernel(const float* __restrict__ X, const float* __restrict__ Y,
                 float* __restrict__ out)
{
    __shared__ __align__(16) _Float16 s_x[SROWS][SPITCH];   // 8448 B
    __shared__ __align__(16) _Float16 s_y[SROWS][SPITCH];   // 8448 B
    __shared__ __align__(16) _Float16 s_ht[2][TW][HPITCH];  // 12288 B
    __shared__ _Float16 s_wtab[16];

    const int tid  = threadIdx.x;
    const int lane = tid & 63;
    const int wv   = tid >> 6;          // wave id = outcol chunk
    const int col0 = blockIdx.x * TW;
    const int row0 = blockIdx.y * TH;
    const int n    = blockIdx.z;

    if (tid < 16) s_wtab[tid] = (tid < 11) ? (_Float16)WF[tid] : (_Float16)0.f;
    // zero-fill pad rows 42..47 once (never overwritten: stage loop r<42)
    {
        const _Float16 z0 = (_Float16)0.f;
        const half4 z4 = {z0, z0, z0, z0};
        for (int i = tid; i < (SROWS - SREAL) * (SCOLS / 4); i += 256) {
            int r = SREAL + i / (SCOLS / 4), c4 = (i % (SCOLS / 4)) * 4;
            *(half4*)&s_x[r][c4] = z4;
            *(half4*)&s_y[r][c4] = z4;
        }
    }
    __syncthreads();

    // banded weight fragment B[k][n] = W[k-n]; lane: n=lane&15, k=(lane>>4)*8+j
    half8 bfrag;
    {
        const int bn = lane & 15, kq = (lane >> 4) * 8;
        #pragma unroll
        for (int j = 0; j < 8; ++j) {
            int kk = kq + j - bn;
            kk = (kk < 0 || kk > 10) ? 11 : kk;   // index 11 holds 0
            bfrag[j] = s_wtab[kk];
        }
    }

    float acc[2][4] = {{0.f,0.f,0.f,0.f},{0.f,0.f,0.f,0.f}};

    const size_t plane = (size_t)HH * WW;
    const float* Xn = X + (size_t)n * CC * plane;
    const float* Yn = Y + (size_t)n * CC * plane;
    const bool fastcol = (col0 + SCOLS <= WW);    // blocks x=0..6

    const floatv4 zf = {0.f, 0.f, 0.f, 0.f};
    const int arow = lane & 15;              // A-operand m row sel
    const int aq   = lane >> 4;              // A-operand k quad
    const int crow = (lane >> 4) * 4;        // C-layout row base

    for (int ch = 0; ch < CC; ++ch) {
        const float* Xc = Xn + (size_t)ch * plane;
        const float* Yc = Yn + (size_t)ch * plane;

        if (ch > 0) __syncthreads();   // prev compute's s_x/s_y reads done

        // ---- stage x,y (42 rows x 80 cols, f16) ----
        if (fastcol) {
            for (int i = tid; i < SREAL * (SCOLS / 4); i += 256) {  // 840
                int r = i / (SCOLS / 4), c4 = (i % (SCOLS / 4)) * 4;
                int gr = row0 + r; gr = gr < HH ? gr : HH - 1;
                float4 vx = *(const float4*)(Xc + (size_t)gr * WW + col0 + c4);
                float4 vy = *(const float4*)(Yc + (size_t)gr * WW + col0 + c4);
                half4 hx = {(_Float16)vx.x, (_Float16)vx.y,
                            (_Float16)vx.z, (_Float16)vx.w};
                half4 hy = {(_Float16)vy.x, (_Float16)vy.y,
                            (_Float16)vy.z, (_Float16)vy.w};
                *(half4*)&s_x[r][c4] = hx;
                *(half4*)&s_y[r][c4] = hy;
            }
        } else {
            for (int i = tid; i < SREAL * (SCOLS / 4); i += 256) {
                int r = i / (SCOLS / 4), c4 = (i % (SCOLS / 4)) * 4;
                int gr = row0 + r; gr = gr < HH ? gr : HH - 1;
                float ax[4], ay[4];
                #pragma unroll
                for (int e = 0; e < 4; ++e) {
                    int gw = col0 + c4 + e; gw = gw < WW ? gw : WW - 1;
                    ax[e] = Xc[(size_t)gr * WW + gw];
                    ay[e] = Yc[(size_t)gr * WW + gw];
                }
                half4 hx = {(_Float16)ax[0], (_Float16)ax[1],
                            (_Float16)ax[2], (_Float16)ax[3]};
                half4 hy = {(_Float16)ay[0], (_Float16)ay[1],
                            (_Float16)ay[2], (_Float16)ay[3]};
                *(half4*)&s_x[r][c4] = hx;
                *(half4*)&s_y[r][c4] = hy;
            }
        }
        __syncthreads();

        // ---- load shared x/y A-fragments (reused by all 5 quantities) ----
        half8 axf[3], ayf[3];
        #pragma unroll
        for (int rc = 0; rc < 3; ++rc) {
            axf[rc] = *(const half8*)&s_x[rc*16 + arow][wv*16 + aq*8];
            ayf[rc] = *(const half8*)&s_y[rc*16 + arow][wv*16 + aq*8];
        }

        // ---- H + V MFMA per quantity (ping-pong s_ht, wave-private) ----
        floatv4 vfr[5][2];
        #pragma unroll
        for (int q = 0; q < 5; ++q) {
            _Float16* hb = &s_ht[q & 1][0][0];
            #pragma unroll
            for (int rc = 0; rc < 3; ++rc) {
                half8 a;
                if      (q == 0) a = axf[rc];
                else if (q == 1) a = ayf[rc];
                else if (q == 2) a = axf[rc] * axf[rc];
                else if (q == 3) a = ayf[rc] * ayf[rc];
                else             a = axf[rc] * ayf[rc];
                floatv4 d = __builtin_amdgcn_mfma_f32_16x16x32_f16(
                    a, bfrag, zf, 0, 0, 0);
                half4 h = {(_Float16)d[0], (_Float16)d[1],
                           (_Float16)d[2], (_Float16)d[3]};
                *(half4*)&hb[(wv*16 + arow) * HPITCH + rc*16 + crow] = h;
            }
            #pragma unroll
            for (int b = 0; b < 2; ++b) {
                half8 av = *(const half8*)
                    &hb[(wv*16 + arow) * HPITCH + b*16 + aq*8];
                vfr[q][b] = __builtin_amdgcn_mfma_f32_16x16x32_f16(
                    av, bfrag, zf, 0, 0, 0);
            }
        }

        // ---- SSIM on V fragments ----
        #pragma unroll
        for (int b = 0; b < 2; ++b) {
            #pragma unroll
            for (int p = 0; p < 4; ++p) {
                float m1 = vfr[0][b][p], m2 = vfr[1][b][p];
                float exx = vfr[2][b][p], eyy = vfr[3][b][p],
                      exy = vfr[4][b][p];
                float m1s = m1*m1, m2s = m2*m2, m12 = m1*m2;
                float s1 = exx - m1s, s2 = eyy - m2s, s12 = exy - m12;
                float n1 = 2.f*m12 + C1c, d1 = m1s + m2s + C1c;
                float n2 = 2.f*s12 + C2c, d2 = s1 + s2 + C2c;
                acc[b][p] = fmaf(n1 * n2, __builtin_amdgcn_rcpf(d1 * d2),
                                 acc[b][p]);
            }
        }
    }

    // ---- epilogue: 1 - mean over channels ----
    #pragma unroll
    for (int b = 0; b < 2; ++b) {
        const int orow = row0 + b*16 + arow;
        const int ocol = col0 + wv*16 + crow;
        if (orow < OH) {
            float r0v = 1.f - acc[b][0] * (1.f/3.f);
            float r1v = 1.f - acc[b][1] * (1.f/3.f);
            float r2v = 1.f - acc[b][2] * (1.f/3.f);
            float r3v = 1.f - acc[b][3] * (1.f/3.f);
            size_t base = ((size_t)n * OH + orow) * OW + ocol;
            if (ocol + 3 < OW) {
                *(float2*)(out + base)     = make_float2(r0v, r1v);
                *(float2*)(out + base + 2) = make_float2(r2v, r3v);
            } else {
                float rs[4] = {r0v, r1v, r2v, r3v};
                #pragma unroll
                for (int p = 0; p < 4; ++p)
                    if (ocol + p < OW) out[base + p] = rs[p];
            }
        }
    }
}

} // namespace

extern "C" void kernel_launch(void* const* d_in, const int* in_sizes, int n_in,
                              void* d_out, int out_size, void* d_ws, size_t ws_size,
                              hipStream_t stream) {
    const float* X = (const float*)d_in[0];
    const float* Y = (const float*)d_in[1];
    float* out = (float*)d_out;

    dim3 grid((OW + TW - 1) / TW,   // 8
              (OH + TH - 1) / TH,   // 16
              NN);                  // 16
    ssim_kernel<<<grid, 256, 0, stream>>>(X, Y, out);
}